// Round 1
// baseline (370.346 us; speedup 1.0000x reference)
//
#include <hip/hip_runtime.h>
#include <hip/hip_bf16.h>
#include <cstdint>

typedef unsigned short u16;
typedef __bf16 bf16x8 __attribute__((ext_vector_type(8)));
typedef float f32x4 __attribute__((ext_vector_type(4)));
typedef unsigned short u16x8 __attribute__((ext_vector_type(8)));
typedef unsigned short u16x4 __attribute__((ext_vector_type(4)));

#define B_ 2
#define T_ 2048
#define C_ 2048
#define NH_ 16
#define NKV_ 4
#define HD_ 128
#define SCALE_ 0.08838834764831845f  // 1/sqrt(128)

__device__ __forceinline__ u16 f2bf(float f) {
    unsigned u = __builtin_bit_cast(unsigned, f);
    unsigned r = u + 0x7FFFu + ((u >> 16) & 1u);
    return (u16)(r >> 16);
}

__device__ __forceinline__ void gl16(const void* g, void* l) {
    auto gp = reinterpret_cast<const __attribute__((address_space(1))) unsigned*>(
        reinterpret_cast<uintptr_t>(g));
    auto lp = reinterpret_cast<__attribute__((address_space(3))) unsigned*>(
        reinterpret_cast<uintptr_t>(l));
    __builtin_amdgcn_global_load_lds(gp, lp, 16, 0, 0);
}

// ---------- transpose + fp32->bf16 convert: in [2048][N] -> out [N][2048] ----------
__global__ void transpose_conv(const float* __restrict__ in, u16* __restrict__ out, int N) {
    __shared__ float tile[32][33];
    int n0 = blockIdx.x * 32, k0 = blockIdx.y * 32;
    int tx = threadIdx.x, ty = threadIdx.y;  // 32 x 8
#pragma unroll
    for (int i = 0; i < 4; ++i)
        tile[ty * 4 + i][tx] = in[(size_t)(k0 + ty * 4 + i) * N + n0 + tx];
    __syncthreads();
#pragma unroll
    for (int i = 0; i < 4; ++i)
        out[(size_t)(n0 + ty * 4 + i) * 2048 + k0 + tx] = f2bf(tile[tx][ty * 4 + i]);
}

// ---------- fp32 -> bf16 convert (x), 4 elems/thread ----------
__global__ void convert4(const float4* __restrict__ in, u16* __restrict__ out) {
    int i = blockIdx.x * 256 + threadIdx.x;
    float4 v = in[i];
    u16x4 o;
    o[0] = f2bf(v.x); o[1] = f2bf(v.y); o[2] = f2bf(v.z); o[3] = f2bf(v.w);
    ((u16x4*)out)[i] = o;
}

// ---------- GEMM: C[M][N] f32 = A[M][K] bf16 * BT[N][K] bf16 (B transposed) ----------
// m97 structure: 128x128 tile, BK=64, 4 waves (2x2), global_load_lds staging.
__global__ __launch_bounds__(256, 2) void gemm_bf16(const u16* __restrict__ A,
                                                    const u16* __restrict__ BT,
                                                    float* __restrict__ C, int N, int K) {
    __shared__ __align__(16) u16 As[128 * 64];
    __shared__ __align__(16) u16 Bs[128 * 64];
    int t = threadIdx.x;
    int w = t >> 6, l = t & 63;
    int wr = w >> 1, wc = w & 1;
    int lg = l >> 4, lr = l & 15;
    int m0 = blockIdx.y * 128, n0 = blockIdx.x * 128;
    f32x4 acc[4][4] = {};

    int ar = t >> 3;              // tile row of this thread's 16B chunk
    int acb = (t & 7) * 16;       // byte offset within the 128B row
    const char* Abase = (const char*)(A + (size_t)(m0 + ar) * K) + acb;
    const char* Bbase = (const char*)(BT + (size_t)(n0 + ar) * K) + acb;
    char* AsB = (char*)As + t * 16;
    char* BsB = (char*)Bs + t * 16;

    for (int kt = 0; kt < K; kt += 64) {
        if (kt) __syncthreads();
#pragma unroll
        for (int i = 0; i < 4; ++i) {
            gl16(Abase + (size_t)(i * 32) * K * 2 + (size_t)kt * 2, AsB + i * 4096);
            gl16(Bbase + (size_t)(i * 32) * K * 2 + (size_t)kt * 2, BsB + i * 4096);
        }
        __syncthreads();
#pragma unroll
        for (int kk = 0; kk < 2; ++kk) {
            bf16x8 af[4], bfr[4];
#pragma unroll
            for (int m = 0; m < 4; ++m)
                af[m] = *(const bf16x8*)(As + (wr * 64 + m * 16 + lr) * 64 + kk * 32 + lg * 8);
#pragma unroll
            for (int n = 0; n < 4; ++n)
                bfr[n] = *(const bf16x8*)(Bs + (wc * 64 + n * 16 + lr) * 64 + kk * 32 + lg * 8);
#pragma unroll
            for (int m = 0; m < 4; ++m)
#pragma unroll
                for (int n = 0; n < 4; ++n)
                    acc[m][n] = __builtin_amdgcn_mfma_f32_16x16x32_bf16(af[m], bfr[n], acc[m][n], 0, 0, 0);
        }
    }
#pragma unroll
    for (int m = 0; m < 4; ++m) {
        int row = m0 + wr * 64 + m * 16 + lg * 4;
#pragma unroll
        for (int n = 0; n < 4; ++n) {
            int col = n0 + wc * 64 + n * 16 + lr;
            float* Cp = C + (size_t)row * N + col;
#pragma unroll
            for (int r = 0; r < 4; ++r)
                Cp[(size_t)r * N] = acc[m][n][r];
        }
    }
}

// ---------- RoPE + RMSNorm on q and k. One wave per 128-elem head-vector ----------
// qkv: [4096][3072] f32.  qh: [B][NH][T][128] bf16.  kh: [B][NKV][T][128] bf16.
__global__ void rope_rms(const float* __restrict__ qkv, const float* __restrict__ cs,
                         const float* __restrict__ sn, u16* __restrict__ qh,
                         u16* __restrict__ kh) {
    int task = blockIdx.x * 4 + (threadIdx.x >> 6);
    int l = threadIdx.x & 63;
    const float* in;
    u16* out;
    int tpos;
    if (task < 65536) {               // q: 4096 rows * 16 heads
        int row = task >> 4, h = task & 15;
        in = qkv + (size_t)row * 3072 + h * 128;
        int b = row >> 11; tpos = row & 2047;
        out = qh + ((size_t)(b * NH_ + h) * T_ + tpos) * HD_;
    } else {                          // k: 4096 rows * 4 heads
        int t2 = task - 65536;
        int row = t2 >> 2, h = t2 & 3;
        in = qkv + (size_t)row * 3072 + 2048 + h * 128;
        int b = row >> 11; tpos = row & 2047;
        out = kh + ((size_t)(b * NKV_ + h) * T_ + tpos) * HD_;
    }
    float x1 = in[l], x2 = in[l + 64];
    float c = cs[tpos * 64 + l], s = sn[tpos * 64 + l];
    float o1 = x1 * c + x2 * s;
    float o2 = -x1 * s + x2 * c;
    float ss = o1 * o1 + o2 * o2;
#pragma unroll
    for (int m = 1; m < 64; m <<= 1) ss += __shfl_xor(ss, m);
    float r = rsqrtf(ss * (1.0f / 128.0f) + 1.1920929e-07f);
    out[l] = f2bf(o1 * r);
    out[l + 64] = f2bf(o2 * r);
}

// ---------- extract v cols from qkv, convert to bf16 [B][NKV][T][128] ----------
__global__ void extract_v(const float* __restrict__ qkv, u16* __restrict__ vh) {
    int i = blockIdx.x * 256 + threadIdx.x;  // 0..2097151
    int d = i & 127;
    int tt = (i >> 7) & 2047;
    int kvh = (i >> 18) & 3;
    int b = i >> 20;
    int row = b * 2048 + tt;
    vh[i] = f2bf(qkv[(size_t)row * 3072 + 2560 + kvh * 128 + d]);
}

// ---------- causal GQA flash attention ----------
// Q [B][NH][T][128], K/V [B][NKV][T][128] bf16 -> Y [B*T][2048] bf16 (cols h*128+d)
// 4 waves x 32 q-rows, KVBLK=32.
__global__ __launch_bounds__(256, 2) void attn(const u16* __restrict__ Q,
                                               const u16* __restrict__ Kk,
                                               const u16* __restrict__ V,
                                               u16* __restrict__ Y) {
    int bh = blockIdx.y;
    int b = bh >> 4, h = bh & 15, kvh = h >> 2;
    int q0 = blockIdx.x * 128;
    int t = threadIdx.x, w = t >> 6, l = t & 63;
    int lg = l >> 4, lr = l & 15;
    const u16* Qp = Q + (size_t)(b * NH_ + h) * T_ * HD_;
    const u16* Kp = Kk + (size_t)(b * NKV_ + kvh) * T_ * HD_;
    const u16* Vp = V + (size_t)(b * NKV_ + kvh) * T_ * HD_;
    int qw = q0 + w * 32;

    __shared__ __align__(16) u16 Vt[128][40];     // V^T [hd][key], pad 8
    __shared__ __align__(16) u16 P[4][32][40];    // per-wave P [q][key], pad 8

    bf16x8 aq[2][4];
#pragma unroll
    for (int qf = 0; qf < 2; ++qf)
#pragma unroll
        for (int ch = 0; ch < 4; ++ch)
            aq[qf][ch] = *(const bf16x8*)(Qp + (size_t)(qw + qf * 16 + lr) * HD_ + ch * 32 + lg * 8);

    f32x4 acc_o[2][8] = {};
    float m_run[2][4], l_run[2][4];
#pragma unroll
    for (int qf = 0; qf < 2; ++qf)
#pragma unroll
        for (int r = 0; r < 4; ++r) { m_run[qf][r] = -1e30f; l_run[qf][r] = 0.0f; }

    int nkv = (q0 + 128) / 32;
    for (int kb = 0; kb < nkv; ++kb) {
        int kv0 = kb * 32;
        if (kb) __syncthreads();
        {   // stage V^T: thread -> (key pair t&15, hd group t>>4)
            int kp = t & 15, hg = t >> 4;
            u16x8 va = *(const u16x8*)(Vp + (size_t)(kv0 + 2 * kp) * HD_ + hg * 8);
            u16x8 vb = *(const u16x8*)(Vp + (size_t)(kv0 + 2 * kp + 1) * HD_ + hg * 8);
#pragma unroll
            for (int j = 0; j < 8; ++j) {
                unsigned pk = (unsigned)va[j] | ((unsigned)vb[j] << 16);
                *(unsigned*)&Vt[hg * 8 + j][2 * kp] = pk;
            }
        }
        __syncthreads();

        // S = Q K^T  (16 MFMA)
        f32x4 s[2][2] = {};
#pragma unroll
        for (int ch = 0; ch < 4; ++ch)
#pragma unroll
            for (int kf = 0; kf < 2; ++kf) {
                bf16x8 bk = *(const bf16x8*)(Kp + (size_t)(kv0 + kf * 16 + lr) * HD_ + ch * 32 + lg * 8);
#pragma unroll
                for (int qf = 0; qf < 2; ++qf)
                    s[qf][kf] = __builtin_amdgcn_mfma_f32_16x16x32_bf16(aq[qf][ch], bk, s[qf][kf], 0, 0, 0);
            }

        // mask + online softmax
#pragma unroll
        for (int qf = 0; qf < 2; ++qf) {
            float sv[2][4], mt[4];
#pragma unroll
            for (int r = 0; r < 4; ++r) {
                int qrow = qw + qf * 16 + lg * 4 + r;
#pragma unroll
                for (int kf = 0; kf < 2; ++kf) {
                    int key = kv0 + kf * 16 + lr;
                    float x = s[qf][kf][r] * SCALE_;
                    if (key > qrow) x = -1e30f;
                    sv[kf][r] = x;
                }
                mt[r] = fmaxf(sv[0][r], sv[1][r]);
            }
#pragma unroll
            for (int r = 0; r < 4; ++r) {
                mt[r] = fmaxf(mt[r], __shfl_xor(mt[r], 1));
                mt[r] = fmaxf(mt[r], __shfl_xor(mt[r], 2));
                mt[r] = fmaxf(mt[r], __shfl_xor(mt[r], 4));
                mt[r] = fmaxf(mt[r], __shfl_xor(mt[r], 8));
            }
#pragma unroll
            for (int r = 0; r < 4; ++r) {
                float mn = fmaxf(m_run[qf][r], mt[r]);
                float rs = __expf(m_run[qf][r] - mn);
                m_run[qf][r] = mn;
                float p0 = __expf(sv[0][r] - mn);
                float p1 = __expf(sv[1][r] - mn);
                P[w][qf * 16 + lg * 4 + r][lr] = f2bf(p0);
                P[w][qf * 16 + lg * 4 + r][16 + lr] = f2bf(p1);
                float ps = p0 + p1;
                ps += __shfl_xor(ps, 1);
                ps += __shfl_xor(ps, 2);
                ps += __shfl_xor(ps, 4);
                ps += __shfl_xor(ps, 8);
                l_run[qf][r] = l_run[qf][r] * rs + ps;
#pragma unroll
                for (int oc = 0; oc < 8; ++oc) acc_o[qf][oc][r] *= rs;
            }
        }

        // PV (16 MFMA)
        bf16x8 pa[2];
#pragma unroll
        for (int qf = 0; qf < 2; ++qf)
            pa[qf] = *(const bf16x8*)&P[w][qf * 16 + lr][lg * 8];
#pragma unroll
        for (int oc = 0; oc < 8; ++oc) {
            bf16x8 bv = *(const bf16x8*)&Vt[oc * 16 + lr][lg * 8];
#pragma unroll
            for (int qf = 0; qf < 2; ++qf)
                acc_o[qf][oc] = __builtin_amdgcn_mfma_f32_16x16x32_bf16(pa[qf], bv, acc_o[qf][oc], 0, 0, 0);
        }
    }

    // epilogue: normalize, store bf16 into y [row][h*128 + col]
#pragma unroll
    for (int qf = 0; qf < 2; ++qf) {
        float inv[4];
#pragma unroll
        for (int r = 0; r < 4; ++r) inv[r] = 1.0f / l_run[qf][r];
#pragma unroll
        for (int oc = 0; oc < 8; ++oc)
#pragma unroll
            for (int r = 0; r < 4; ++r) {
                float o = acc_o[qf][oc][r] * inv[r];
                Y[(size_t)(b * T_ + qw + qf * 16 + lg * 4 + r) * 2048 + h * HD_ + oc * 16 + lr] = f2bf(o);
            }
    }
}

extern "C" void kernel_launch(void* const* d_in, const int* in_sizes, int n_in,
                              void* d_out, int out_size, void* d_ws, size_t ws_size,
                              hipStream_t stream) {
    const float* x    = (const float*)d_in[0];
    const float* cosT = (const float*)d_in[1];
    const float* sinT = (const float*)d_in[2];
    const float* wq   = (const float*)d_in[3];
    const float* wk   = (const float*)d_in[4];
    const float* wv   = (const float*)d_in[5];
    const float* wo   = (const float*)d_in[6];
    float* out = (float*)d_out;

    char* ws = (char*)d_ws;
    u16*   wqkvT = (u16*)(ws);                       // [3072][2048] bf16
    u16*   woT   = (u16*)(ws + 12582912);            // [2048][2048] bf16
    u16*   xb    = (u16*)(ws + 20971520);            // [4096][2048] bf16
    float* qkv   = (float*)(ws + 37748736);          // [4096][3072] f32
    u16*   qh    = (u16*)(ws + 88080384);            // [2][16][2048][128] bf16
    u16*   kh    = (u16*)(ws + 104857600);           // [2][4][2048][128] bf16
    u16*   vh    = (u16*)(ws + 109051904);           // [2][4][2048][128] bf16
    u16*   y     = xb;                               // reuse (xb dead after GEMM1)

    transpose_conv<<<dim3(64, 64), dim3(32, 8), 0, stream>>>(wq, wqkvT, 2048);
    transpose_conv<<<dim3(16, 64), dim3(32, 8), 0, stream>>>(wk, wqkvT + (size_t)2048 * 2048, 512);
    transpose_conv<<<dim3(16, 64), dim3(32, 8), 0, stream>>>(wv, wqkvT + (size_t)2560 * 2048, 512);
    transpose_conv<<<dim3(64, 64), dim3(32, 8), 0, stream>>>(wo, woT, 2048);
    convert4<<<8192, 256, 0, stream>>>((const float4*)x, xb);

    gemm_bf16<<<dim3(24, 32), 256, 0, stream>>>(xb, wqkvT, qkv, 3072, 2048);

    rope_rms<<<20480, 256, 0, stream>>>(qkv, cosT, sinT, qh, kh);
    extract_v<<<8192, 256, 0, stream>>>(qkv, vh);

    attn<<<dim3(16, 32), 256, 0, stream>>>(qh, kh, vh, y);

    gemm_bf16<<<dim3(16, 32), 256, 0, stream>>>(y, woT, out, 2048, 2048);
}

// Round 2
// 335.229 us; speedup vs baseline: 1.1048x; 1.1048x over previous
//
#include <hip/hip_runtime.h>
#include <hip/hip_bf16.h>
#include <cstdint>

typedef unsigned short u16;
typedef __bf16 bf16x8 __attribute__((ext_vector_type(8)));
typedef float f32x4 __attribute__((ext_vector_type(4)));
typedef unsigned short u16x8 __attribute__((ext_vector_type(8)));
typedef unsigned short u16x4 __attribute__((ext_vector_type(4)));

#define B_ 2
#define T_ 2048
#define C_ 2048
#define NH_ 16
#define NKV_ 4
#define HD_ 128
// SCALE * log2(e) = (1/sqrt(128)) * 1.4426950408889634
#define K2_ 0.12752004650581538f

__device__ __forceinline__ u16 f2bf(float f) {
    unsigned u = __builtin_bit_cast(unsigned, f);
    unsigned r = u + 0x7FFFu + ((u >> 16) & 1u);
    return (u16)(r >> 16);
}

__device__ __forceinline__ void gl16(const void* g, void* l) {
    auto gp = reinterpret_cast<const __attribute__((address_space(1))) unsigned*>(
        reinterpret_cast<uintptr_t>(g));
    auto lp = reinterpret_cast<__attribute__((address_space(3))) unsigned*>(
        reinterpret_cast<uintptr_t>(l));
    __builtin_amdgcn_global_load_lds(gp, lp, 16, 0, 0);
}

// ---------- transpose + fp32->bf16 convert: in [2048][N] -> out [N][2048] ----------
__global__ void transpose_conv(const float* __restrict__ in, u16* __restrict__ out, int N) {
    __shared__ float tile[32][33];
    int n0 = blockIdx.x * 32, k0 = blockIdx.y * 32;
    int tx = threadIdx.x, ty = threadIdx.y;  // 32 x 8
#pragma unroll
    for (int i = 0; i < 4; ++i)
        tile[ty * 4 + i][tx] = in[(size_t)(k0 + ty * 4 + i) * N + n0 + tx];
    __syncthreads();
#pragma unroll
    for (int i = 0; i < 4; ++i)
        out[(size_t)(n0 + ty * 4 + i) * 2048 + k0 + tx] = f2bf(tile[tx][ty * 4 + i]);
}

// ---------- fp32 -> bf16 convert (x), 4 elems/thread ----------
__global__ void convert4(const float4* __restrict__ in, u16* __restrict__ out) {
    int i = blockIdx.x * 256 + threadIdx.x;
    float4 v = in[i];
    u16x4 o;
    o[0] = f2bf(v.x); o[1] = f2bf(v.y); o[2] = f2bf(v.z); o[3] = f2bf(v.w);
    ((u16x4*)out)[i] = o;
}

// ---------- GEMM: C[M][N] f32 = A[M][K] bf16 * BT[N][K] bf16 (B transposed) ----------
__global__ __launch_bounds__(256, 2) void gemm_bf16(const u16* __restrict__ A,
                                                    const u16* __restrict__ BT,
                                                    float* __restrict__ C, int N, int K) {
    __shared__ __align__(16) u16 As[128 * 64];
    __shared__ __align__(16) u16 Bs[128 * 64];
    int t = threadIdx.x;
    int w = t >> 6, l = t & 63;
    int wr = w >> 1, wc = w & 1;
    int lg = l >> 4, lr = l & 15;
    int m0 = blockIdx.y * 128, n0 = blockIdx.x * 128;
    f32x4 acc[4][4] = {};

    int ar = t >> 3;
    int acb = (t & 7) * 16;
    const char* Abase = (const char*)(A + (size_t)(m0 + ar) * K) + acb;
    const char* Bbase = (const char*)(BT + (size_t)(n0 + ar) * K) + acb;
    char* AsB = (char*)As + t * 16;
    char* BsB = (char*)Bs + t * 16;

    for (int kt = 0; kt < K; kt += 64) {
        if (kt) __syncthreads();
#pragma unroll
        for (int i = 0; i < 4; ++i) {
            gl16(Abase + (size_t)(i * 32) * K * 2 + (size_t)kt * 2, AsB + i * 4096);
            gl16(Bbase + (size_t)(i * 32) * K * 2 + (size_t)kt * 2, BsB + i * 4096);
        }
        __syncthreads();
#pragma unroll
        for (int kk = 0; kk < 2; ++kk) {
            bf16x8 af[4], bfr[4];
#pragma unroll
            for (int m = 0; m < 4; ++m)
                af[m] = *(const bf16x8*)(As + (wr * 64 + m * 16 + lr) * 64 + kk * 32 + lg * 8);
#pragma unroll
            for (int n = 0; n < 4; ++n)
                bfr[n] = *(const bf16x8*)(Bs + (wc * 64 + n * 16 + lr) * 64 + kk * 32 + lg * 8);
#pragma unroll
            for (int m = 0; m < 4; ++m)
#pragma unroll
                for (int n = 0; n < 4; ++n)
                    acc[m][n] = __builtin_amdgcn_mfma_f32_16x16x32_bf16(af[m], bfr[n], acc[m][n], 0, 0, 0);
        }
    }
#pragma unroll
    for (int m = 0; m < 4; ++m) {
        int row = m0 + wr * 64 + m * 16 + lg * 4;
#pragma unroll
        for (int n = 0; n < 4; ++n) {
            int col = n0 + wc * 64 + n * 16 + lr;
            float* Cp = C + (size_t)row * N + col;
#pragma unroll
            for (int r = 0; r < 4; ++r)
                Cp[(size_t)r * N] = acc[m][n][r];
        }
    }
}

// ---------- RoPE + RMSNorm on q and k. One wave per 128-elem head-vector ----------
__global__ void rope_rms(const float* __restrict__ qkv, const float* __restrict__ cs,
                         const float* __restrict__ sn, u16* __restrict__ qh,
                         u16* __restrict__ kh) {
    int task = blockIdx.x * 4 + (threadIdx.x >> 6);
    int l = threadIdx.x & 63;
    const float* in;
    u16* out;
    int tpos;
    if (task < 65536) {               // q: 4096 rows * 16 heads
        int row = task >> 4, h = task & 15;
        in = qkv + (size_t)row * 3072 + h * 128;
        int b = row >> 11; tpos = row & 2047;
        out = qh + ((size_t)(b * NH_ + h) * T_ + tpos) * HD_;
    } else {                          // k: 4096 rows * 4 heads
        int t2 = task - 65536;
        int row = t2 >> 2, h = t2 & 3;
        in = qkv + (size_t)row * 3072 + 2048 + h * 128;
        int b = row >> 11; tpos = row & 2047;
        out = kh + ((size_t)(b * NKV_ + h) * T_ + tpos) * HD_;
    }
    float x1 = in[l], x2 = in[l + 64];
    float c = cs[tpos * 64 + l], s = sn[tpos * 64 + l];
    float o1 = x1 * c + x2 * s;
    float o2 = -x1 * s + x2 * c;
    float ss = o1 * o1 + o2 * o2;
#pragma unroll
    for (int m = 1; m < 64; m <<= 1) ss += __shfl_xor(ss, m);
    float r = rsqrtf(ss * (1.0f / 128.0f) + 1.1920929e-07f);
    out[l] = f2bf(o1 * r);
    out[l + 64] = f2bf(o2 * r);
}

// ---------- V extract + transpose: qkv [4096][3072] f32 -> vt [B*NKV][128][2048] bf16 ----------
__global__ void transpose_v(const float* __restrict__ qkv, u16* __restrict__ vt) {
    __shared__ float tile[32][33];
    int t0 = blockIdx.x * 32;   // 64
    int d0 = blockIdx.y * 32;   // 4
    int bk = blockIdx.z;        // 8 = b*4+kvh
    int b = bk >> 2, kvh = bk & 3;
    int tx = threadIdx.x, ty = threadIdx.y;  // 32 x 8
#pragma unroll
    for (int i = 0; i < 4; ++i)
        tile[ty * 4 + i][tx] =
            qkv[(size_t)(b * 2048 + t0 + ty * 4 + i) * 3072 + 2560 + kvh * 128 + d0 + tx];
    __syncthreads();
#pragma unroll
    for (int i = 0; i < 4; ++i)
        vt[((size_t)bk * 128 + d0 + ty * 4 + i) * 2048 + t0 + tx] = f2bf(tile[tx][ty * 4 + i]);
}

// ---------- causal GQA flash attention, sync-free, 1 wave/block ----------
// Q [B][NH][T][128], K [B][NKV][T][128], Vt [B][NKV][128][T] bf16 -> Y [B*T][2048] bf16
__device__ __forceinline__ void attn_strip(const u16* __restrict__ Qp,
                                           const u16* __restrict__ Kp,
                                           const u16* __restrict__ Vp,
                                           u16* __restrict__ Yp, int s, u16* P) {
    int l = threadIdx.x;
    int lg = l >> 4, lr = l & 15;
    int qw = s * 32;

    bf16x8 aq[2][4];
#pragma unroll
    for (int qf = 0; qf < 2; ++qf)
#pragma unroll
        for (int ch = 0; ch < 4; ++ch)
            aq[qf][ch] = *(const bf16x8*)(Qp + (size_t)(qw + qf * 16 + lr) * HD_ + ch * 32 + lg * 8);

    f32x4 acc[2][8] = {};
    float m2[2][4], lp[2][4];
#pragma unroll
    for (int qf = 0; qf < 2; ++qf)
#pragma unroll
        for (int r = 0; r < 4; ++r) { m2[qf][r] = -1e30f; lp[qf][r] = 0.0f; }

    int kend = qw + 32;
    for (int kv0 = 0; kv0 < kend; kv0 += 64) {
        bool nm = (kv0 + 63 > qw);  // diagonal block needs causal mask
        // ---- S = Q K^T over 64 keys ----
        f32x4 sc[2][4] = {};
#pragma unroll
        for (int ch = 0; ch < 4; ++ch)
#pragma unroll
            for (int kf = 0; kf < 4; ++kf) {
                bf16x8 bk = *(const bf16x8*)(Kp + (size_t)(kv0 + kf * 16 + lr) * HD_ + ch * 32 + lg * 8);
                sc[0][kf] = __builtin_amdgcn_mfma_f32_16x16x32_bf16(aq[0][ch], bk, sc[0][kf], 0, 0, 0);
                sc[1][kf] = __builtin_amdgcn_mfma_f32_16x16x32_bf16(aq[1][ch], bk, sc[1][kf], 0, 0, 0);
            }
        // ---- scale to log2 domain + mask + row max ----
        float sv[2][4][4];
        float mx[2][4];
#pragma unroll
        for (int qf = 0; qf < 2; ++qf)
#pragma unroll
            for (int r = 0; r < 4; ++r) {
                int row = qw + qf * 16 + lg * 4 + r;
#pragma unroll
                for (int kf = 0; kf < 4; ++kf) {
                    float x = sc[qf][kf][r] * K2_;
                    if (nm) {
                        int key = kv0 + kf * 16 + lr;
                        x = (key > row) ? -1e38f : x;
                    }
                    sv[qf][r][kf] = x;
                }
                mx[qf][r] = fmaxf(fmaxf(sv[qf][r][0], sv[qf][r][1]),
                                  fmaxf(sv[qf][r][2], sv[qf][r][3]));
            }
#pragma unroll
        for (int qf = 0; qf < 2; ++qf)
#pragma unroll
            for (int r = 0; r < 4; ++r) {
                float m = mx[qf][r];
                m = fmaxf(m, __shfl_xor(m, 1));
                m = fmaxf(m, __shfl_xor(m, 2));
                m = fmaxf(m, __shfl_xor(m, 4));
                m = fmaxf(m, __shfl_xor(m, 8));
                mx[qf][r] = m;
            }
        // ---- defer-max: only rescale when max grew by > 8 (log2 domain) ----
        bool upd = false;
#pragma unroll
        for (int qf = 0; qf < 2; ++qf)
#pragma unroll
            for (int r = 0; r < 4; ++r) upd |= (mx[qf][r] > m2[qf][r] + 8.0f);
        if (__any(upd)) {
#pragma unroll
            for (int qf = 0; qf < 2; ++qf)
#pragma unroll
                for (int r = 0; r < 4; ++r) {
                    float mn = fmaxf(m2[qf][r], mx[qf][r]);
                    float rs = exp2f(m2[qf][r] - mn);
                    m2[qf][r] = mn;
                    lp[qf][r] *= rs;
#pragma unroll
                    for (int oc = 0; oc < 8; ++oc) acc[qf][oc] *= rs;
                }
        }
        // ---- p = 2^(s - m), accumulate partial l, stage P ----
#pragma unroll
        for (int qf = 0; qf < 2; ++qf)
#pragma unroll
            for (int r = 0; r < 4; ++r) {
                float m = m2[qf][r];
                float ps = 0.0f;
#pragma unroll
                for (int kf = 0; kf < 4; ++kf) {
                    float p = exp2f(sv[qf][r][kf] - m);
                    ps += p;
                    P[(qf * 16 + lg * 4 + r) * 72 + kf * 16 + lr] = f2bf(p);
                }
                lp[qf][r] += ps;
            }
        // ---- O += P V ----
        bf16x8 ap[2][2];
#pragma unroll
        for (int qf = 0; qf < 2; ++qf)
#pragma unroll
            for (int kk = 0; kk < 2; ++kk)
                ap[qf][kk] = *(const bf16x8*)&P[(qf * 16 + lr) * 72 + kk * 32 + lg * 8];
#pragma unroll
        for (int oc = 0; oc < 8; ++oc)
#pragma unroll
            for (int kk = 0; kk < 2; ++kk) {
                bf16x8 bv = *(const bf16x8*)(Vp + (size_t)(oc * 16 + lr) * T_ + kv0 + kk * 32 + lg * 8);
                acc[0][oc] = __builtin_amdgcn_mfma_f32_16x16x32_bf16(ap[0][kk], bv, acc[0][oc], 0, 0, 0);
                acc[1][oc] = __builtin_amdgcn_mfma_f32_16x16x32_bf16(ap[1][kk], bv, acc[1][oc], 0, 0, 0);
            }
    }
    // ---- epilogue: reduce l over lanes, normalize, store ----
    float inv_[2][4];
#pragma unroll
    for (int qf = 0; qf < 2; ++qf)
#pragma unroll
        for (int r = 0; r < 4; ++r) {
            float lt = lp[qf][r];
            lt += __shfl_xor(lt, 1);
            lt += __shfl_xor(lt, 2);
            lt += __shfl_xor(lt, 4);
            lt += __shfl_xor(lt, 8);
            inv_[qf][r] = 1.0f / lt;
        }
#pragma unroll
    for (int qf = 0; qf < 2; ++qf)
#pragma unroll
        for (int oc = 0; oc < 8; ++oc)
#pragma unroll
            for (int r = 0; r < 4; ++r)
                Yp[(size_t)(qw + qf * 16 + lg * 4 + r) * 2048 + oc * 16 + lr] =
                    f2bf(acc[qf][oc][r] * inv_[qf][r]);
}

__global__ __launch_bounds__(64, 1) void attn(const u16* __restrict__ Q,
                                              const u16* __restrict__ Kk,
                                              const u16* __restrict__ V,
                                              u16* __restrict__ Y) {
    __shared__ __align__(16) u16 P[32 * 72];
    int bh = blockIdx.y;
    int b = bh >> 4, h = bh & 15, kvh = h >> 2;
    int pair = blockIdx.x;  // 0..31
    const u16* Qp = Q + (size_t)(b * NH_ + h) * T_ * HD_;
    const u16* Kp = Kk + (size_t)(b * NKV_ + kvh) * T_ * HD_;
    const u16* Vp = V + (size_t)(b * NKV_ + kvh) * HD_ * T_;
    u16* Yp = Y + (size_t)(b * T_) * 2048 + h * HD_;
    attn_strip(Qp, Kp, Vp, Yp, pair, P);
    attn_strip(Qp, Kp, Vp, Yp, 63 - pair, P);
}

extern "C" void kernel_launch(void* const* d_in, const int* in_sizes, int n_in,
                              void* d_out, int out_size, void* d_ws, size_t ws_size,
                              hipStream_t stream) {
    const float* x    = (const float*)d_in[0];
    const float* cosT = (const float*)d_in[1];
    const float* sinT = (const float*)d_in[2];
    const float* wq   = (const float*)d_in[3];
    const float* wk   = (const float*)d_in[4];
    const float* wv   = (const float*)d_in[5];
    const float* wo   = (const float*)d_in[6];
    float* out = (float*)d_out;

    char* ws = (char*)d_ws;
    u16*   wqkvT = (u16*)(ws);                       // [3072][2048] bf16
    u16*   woT   = (u16*)(ws + 12582912);            // [2048][2048] bf16
    u16*   xb    = (u16*)(ws + 20971520);            // [4096][2048] bf16
    float* qkv   = (float*)(ws + 37748736);          // [4096][3072] f32
    u16*   qh    = (u16*)(ws + 88080384);            // [2][16][2048][128] bf16
    u16*   kh    = (u16*)(ws + 104857600);           // [2][4][2048][128] bf16
    u16*   vt    = (u16*)(ws + 109051904);           // [2][4][128][2048] bf16 (V^T)
    u16*   y     = xb;                               // reuse (xb dead after GEMM1)

    transpose_conv<<<dim3(64, 64), dim3(32, 8), 0, stream>>>(wq, wqkvT, 2048);
    transpose_conv<<<dim3(16, 64), dim3(32, 8), 0, stream>>>(wk, wqkvT + (size_t)2048 * 2048, 512);
    transpose_conv<<<dim3(16, 64), dim3(32, 8), 0, stream>>>(wv, wqkvT + (size_t)2560 * 2048, 512);
    transpose_conv<<<dim3(64, 64), dim3(32, 8), 0, stream>>>(wo, woT, 2048);
    convert4<<<8192, 256, 0, stream>>>((const float4*)x, xb);

    gemm_bf16<<<dim3(24, 32), 256, 0, stream>>>(xb, wqkvT, qkv, 3072, 2048);

    rope_rms<<<20480, 256, 0, stream>>>(qkv, cosT, sinT, qh, kh);
    transpose_v<<<dim3(64, 4, 8), dim3(32, 8), 0, stream>>>(qkv, vt);

    attn<<<dim3(32, 32), 64, 0, stream>>>(qh, kh, vt, y);

    gemm_bf16<<<dim3(16, 32), 256, 0, stream>>>(y, woT, out, 2048, 2048);
}